// Round 10
// baseline (390.399 us; speedup 1.0000x reference)
//
#include <hip/hip_runtime.h>
#include <math.h>

#define TSEQ 2048
#define BATCH 4
#define NH 16
#define DH 64
#define DM 1024
#define NREL 129
#define NEGBIG (-1.0e30f)
#define FIXMAX 8.0f

typedef unsigned short u16;
typedef unsigned int u32;
typedef __attribute__((ext_vector_type(8))) short bf16x8;
typedef __attribute__((ext_vector_type(4))) float f32x4;
typedef __attribute__((ext_vector_type(4))) unsigned short u16x4;

typedef __attribute__((address_space(3))) void lds_void;
typedef const __attribute__((address_space(1))) void g_void;

__device__ inline u16 f2b(float f) {
    union { float f; u32 i; } c; c.f = f;
    u32 x = c.i;
    return (u16)((x + 0x7fffu + ((x >> 16) & 1u)) >> 16);
}

// packed RNE f32->bf16 pair: D.lo = bf16(lo), D.hi = bf16(hi).
// Bit-identical to f2b for positive normal/zero inputs (both RNE).
__device__ inline u32 cvtpk(float lo, float hi) {
    u32 r;
    asm("v_cvt_pk_bf16_f32 %0, %1, %2" : "=v"(r) : "v"(lo), "v"(hi));
    return r;
}

__global__ __launch_bounds__(256) void fill_kernel(float* __restrict__ out, int n, float v) {
    for (int i = blockIdx.x * 256 + threadIdx.x; i < n; i += gridDim.x * 256)
        out[i] = v;
}

// ---------------- Fused LayerNorm + weight cvt (independent work, one dispatch) --
// blocks [0, B*T): LN row; blocks [B*T, B*T + 3*2^18/256): cvt of Wq*1/8,Wk,Wv.
__global__ __launch_bounds__(256) void lncvt_kernel(const float* __restrict__ x,
        const float* __restrict__ gamma, const float* __restrict__ beta,
        u16* __restrict__ xn, const float* __restrict__ wa,
        const float* __restrict__ wb, const float* __restrict__ wc,
        u16* __restrict__ wdst) {
    const int tid = threadIdx.x;
    if (blockIdx.x >= BATCH * TSEQ) {
        const int i = (blockIdx.x - BATCH * TSEQ) * 256 + tid;  // vec4 idx
        const int m = i >> 18;
        const int j = i & 0x3FFFF;
        const float* src = m == 0 ? wa : (m == 1 ? wb : wc);
        const float scale = m == 0 ? 0.125f : 1.0f;
        f32x4 v = *(const f32x4*)(src + (size_t)j * 4);
        u16x4 o;
        o.x = f2b(v.x * scale); o.y = f2b(v.y * scale);
        o.z = f2b(v.z * scale); o.w = f2b(v.w * scale);
        *(u16x4*)(wdst + (size_t)i * 4) = o;
        return;
    }
    const int row = blockIdx.x;
    const float* xr = x + (size_t)row * DM;
    f32x4 xv = *(const f32x4*)(xr + tid * 4);
    float s = xv.x + xv.y + xv.z + xv.w;
    float s2 = xv.x*xv.x + xv.y*xv.y + xv.z*xv.z + xv.w*xv.w;
#pragma unroll
    for (int off = 32; off > 0; off >>= 1) {
        s  += __shfl_down(s, off, 64);
        s2 += __shfl_down(s2, off, 64);
    }
    __shared__ alignas(16) float red[8];
    const int wv = tid >> 6, ln = tid & 63;
    if (ln == 0) { red[wv] = s; red[4 + wv] = s2; }
    __syncthreads();
    s  = red[0] + red[1] + red[2] + red[3];
    s2 = red[4] + red[5] + red[6] + red[7];
    const float mu = s * (1.0f / DM);
    float var = s2 * (1.0f / DM) - mu * mu;
    var = var > 0.0f ? var : 0.0f;
    const float rstd = rsqrtf(var + 1e-5f);
    f32x4 gv = *(const f32x4*)(gamma + tid * 4);
    f32x4 bv = *(const f32x4*)(beta + tid * 4);
    u16x4 ov;
    ov.x = f2b((xv.x - mu) * rstd * gv.x + bv.x);
    ov.y = f2b((xv.y - mu) * rstd * gv.y + bv.y);
    ov.z = f2b((xv.z - mu) * rstd * gv.z + bv.z);
    ov.w = f2b((xv.w - mu) * rstd * gv.w + bv.w);
    *(u16x4*)(xn + (size_t)row * DM + tid * 4) = ov;
}

__global__ __launch_bounds__(256) void cvt1_kernel(const float* __restrict__ src,
        u16* __restrict__ dst, int n4) {
    const int i = blockIdx.x * 256 + threadIdx.x;
    if (i >= n4) return;
    f32x4 v = *(const f32x4*)(src + (size_t)i * 4);
    u16x4 o;
    o.x = f2b(v.x); o.y = f2b(v.y); o.z = f2b(v.z); o.w = f2b(v.w);
    *(u16x4*)(dst + (size_t)i * 4) = o;
}

// ---------------- QKV GEMM: 256x128 tile, 8 waves, BK=32, 2-phase dbuf ----------
// Round-9 evidence: 128x128/4-wave at 1536 blocks ran 5-resident/CU with a
// 256-block tail (LDS 32KB caps at 5, grid needs 6) -> Occupancy 28%, half the
// cycles in barrier stalls. This shape: 768 blocks = EXACTLY 3/CU (LDS 48KB),
// zero tail, 24 waves/CU. Per-wave geometry (64x64 quadrant, 16 MFMA + 8
// ds_read_b128 per K-step) and both XOR swizzle formulas are unchanged.
#define BM 128
#define BN 128
#define BK 32

// Fragment-major layouts for attention operands (pure permutations of Q/K/V).
// Qf: per bh, per 16-q block: 2 chunks (d 0-31, 32-63) of 512 u16;
//     (t,d) -> chunk (d>>5), slot = ((d>>3)&3)*16 + (t&15), e = d&7.
// Kf: per bh, per 32-j block: 4 chunks {k00,k01,k10,k11}:
//     jr=j&31: hi=(jr>>2)&1, lk=(jr&3)|((jr>>3)<<2); chunk = hi*2 + (d>>5);
//     slot = ((d>>3)&3)*16 + lk, e = d&7.
// Vf: per bh, per 32-j block: 4 chunks dt=d>>4:
//     slot = ((t>>3)&3)*16 + (d&15), e = t&7.
__global__ __launch_bounds__(512, 6) void gemm_qkv(const u16* __restrict__ A,
        const u16* __restrict__ W3, u16* __restrict__ Qb, u16* __restrict__ Kb,
        u16* __restrict__ Vb) {
    __shared__ alignas(16) u16 sh[24576];  // A dbuf [2][8192] + B dbuf [2][4096]
    const int id = blockIdx.x;              // 0..767
    const int xcd = id & 7;
    const int k = id >> 3;                  // 0..95
    const int xv = xcd * 4 + (k & 3);       // m-panel (256 rows): 4 per XCD = 2MB L2
    const int yv = k >> 2;                  // 0..23 (mat, n-panel)
    const int m0 = xv * 256;
    const int mat = yv >> 3;
    const int n0 = (yv & 7) * BN;
    const u16* Wb = W3 + (size_t)mat * DM * DM;
    const int tid = threadIdx.x;
    const int w = tid >> 6;                 // 0..7
    const int lane = tid & 63;
    const int quad = lane >> 4, l16 = lane & 15;
    const int wr = (w >> 1) * 64;           // 0..192 (m quadrant)
    const int wc = (w & 1) * 64;            // 0/64   (n quadrant)

    // pre-swizzled global source slot (sigma(row) = (row>>1)&3 = (lane>>3)&3)
    const int scol = (((lane & 3) ^ ((lane >> 3) & 3))) * 8;
    const int sra = 32 * w + (lane >> 2);   // A stage: wave w rows [32w, 32w+32)
    const int srb = 16 * w + (lane >> 2);   // B stage: wave w rows [16w, 16w+16)
    const u16* ag = A  + (size_t)(m0 + sra) * DM + scol;
    const u16* bg = Wb + (size_t)(n0 + srb) * DM + scol;
    u16* asw = sh + w * 1024;               // chunk 2w base (+ buf*8192)
    u16* bsw = sh + 16384 + w * 512;        // chunk w base  (+ buf*4096)
    const int sx = (quad ^ ((l16 >> 1) & 3)) * 8;   // matching read swizzle

    f32x4 acc[4][4];
#pragma unroll
    for (int i = 0; i < 4; i++)
#pragma unroll
        for (int j = 0; j < 4; j++) acc[i][j] = (f32x4){0.f, 0.f, 0.f, 0.f};

#define QKV_STAGE(buf, kk) do { \
    __builtin_amdgcn_global_load_lds((g_void*)(ag + (kk)),            (lds_void*)(asw + (buf)*8192),       16, 0, 0); \
    __builtin_amdgcn_global_load_lds((g_void*)(ag + (kk) + 16 * DM),  (lds_void*)(asw + (buf)*8192 + 512), 16, 0, 0); \
    __builtin_amdgcn_global_load_lds((g_void*)(bg + (kk)),            (lds_void*)(bsw + (buf)*4096),       16, 0, 0); \
} while (0)

    QKV_STAGE(0, 0);
    __syncthreads();
    for (int k0 = 0; k0 < DM; k0 += BK) {
        const int cur = (k0 >> 5) & 1;
        if (k0 + BK < DM) QKV_STAGE(cur ^ 1, k0 + BK);
        const u16* Ac = sh + cur * 8192;
        const u16* Bc = sh + 16384 + cur * 4096;
        bf16x8 af[4], bfr[4];
#pragma unroll
        for (int mt = 0; mt < 4; mt++)
            af[mt] = *(const bf16x8*)(Ac + (wr + mt * 16 + l16) * BK + sx);
#pragma unroll
        for (int nt = 0; nt < 4; nt++)
            bfr[nt] = *(const bf16x8*)(Bc + (wc + nt * 16 + l16) * BK + sx);
#pragma unroll
        for (int mt = 0; mt < 4; mt++)
#pragma unroll
            for (int nt = 0; nt < 4; nt++)
                acc[mt][nt] = __builtin_amdgcn_mfma_f32_16x16x32_bf16(af[mt], bfr[nt], acc[mt][nt], 0, 0, 0);
        __syncthreads();   // drains next-tile loads (after MFMA cover) + read fence
    }
#undef QKV_STAGE

    // ---- Epilogue: per-wave 4KB LDS staging -> coalesced 1KB chunk stores ----
    u16* outb = mat == 0 ? Qb : (mat == 1 ? Kb : Vb);
    const size_t bh = (size_t)(m0 >> 11) * NH + ((n0 + wc) >> 6);
    const int tq = (m0 & 2047) + wr;                // quadrant first row in batch
    u16* stage = sh + w * 2048;                     // per-wave 4KB (buffers dead now)

#pragma unroll
    for (int p = 0; p < 2; p++) {
#pragma unroll
        for (int mt = 0; mt < 4; mt++) {
#pragma unroll
            for (int ntl = 0; ntl < 2; ntl++) {
                const int nt = p * 2 + ntl;
#pragma unroll
                for (int r = 0; r < 4; r++) {
                    const u16 val = f2b(acc[mt][nt][r]);
                    int a;
                    if (mat == 0) {
                        a = mt * 512
                          + ((ntl * 2 + (l16 >> 3)) * 16 + quad * 4 + r) * 8 + (l16 & 7);
                    } else if (mat == 1) {
                        a = ((mt >> 1) * 2 + (quad & 1)) * 512
                          + ((ntl * 2 + (l16 >> 3)) * 16 + (quad >> 1) * 4 + (mt & 1) * 8 + r) * 8
                          + (l16 & 7);
                    } else {
                        a = ((mt >> 1) * 2 + ntl) * 512
                          + (((mt * 2 + (quad >> 1)) & 3) * 16 + l16) * 8
                          + (quad & 1) * 4 + r;
                    }
                    stage[a] = val;
                }
            }
        }
        // same-wave LDS write->read (short-typed reads alias u16 stores)
#pragma unroll
        for (int c = 0; c < 4; c++) {
            const bf16x8 vv = *(const bf16x8*)(stage + c * 512 + lane * 8);
            size_t gc;
            if (mat == 0)      gc = (bh * 128 + (tq >> 4) + c) * 2 + p;
            else if (mat == 1) gc = (bh * 64 + (tq >> 5) + (c >> 1)) * 4 + (c & 1) * 2 + p;
            else               gc = (bh * 64 + (tq >> 5) + (c >> 1)) * 4 + p * 2 + (c & 1);
            *(bf16x8*)(outb + gc * 512 + lane * 8) = vv;
        }
    }
}

// Output projection + residual: out = y @ Wo^T + x0 (fp32 out).
// Same XCD remap; same 2-phase double-buffered schedule; same LDS slot-swizzle.
__global__ __launch_bounds__(256) void gemm_wo(const u16* __restrict__ A,
        const u16* __restrict__ Wb, const float* __restrict__ X0,
        float* __restrict__ out) {
    __shared__ alignas(16) u16 sh[16384];
    const int id = blockIdx.x + 64 * blockIdx.y;   // 0..511
    const int xcd = id & 7;
    const int k = id >> 3;                          // 0..63
    const int m0 = (xcd * 8 + (k & 7)) * BM;
    const int n0 = (k >> 3) * BN;
    const int tid = threadIdx.x;
    const int w = tid >> 6;
    const int lane = tid & 63;
    const int quad = lane >> 4, l16 = lane & 15;
    const int wr = (w >> 1) * 64;
    const int wc = (w & 1) * 64;

    const int c0 = w * 2;
    const int srow = c0 * 16 + (lane >> 2);
    const int scol = (((lane & 3) ^ ((lane >> 3) & 3))) * 8;
    const u16* ag = A  + (size_t)(m0 + srow) * DM + scol;
    const u16* bg = Wb + (size_t)(n0 + srow) * DM + scol;
    u16* asw = sh + c0 * 512;
    u16* bsw = sh + 8192 + c0 * 512;
    const int sx = (quad ^ ((l16 >> 1) & 3)) * 8;

    f32x4 acc[4][4];
#pragma unroll
    for (int i = 0; i < 4; i++)
#pragma unroll
        for (int j = 0; j < 4; j++) acc[i][j] = (f32x4){0.f, 0.f, 0.f, 0.f};

#define WO_STAGE(buf, kk) do { \
    __builtin_amdgcn_global_load_lds((g_void*)(ag + (kk)),            (lds_void*)(asw + (buf)*4096),       16, 0, 0); \
    __builtin_amdgcn_global_load_lds((g_void*)(ag + (kk) + 16 * DM),  (lds_void*)(asw + (buf)*4096 + 512), 16, 0, 0); \
    __builtin_amdgcn_global_load_lds((g_void*)(bg + (kk)),            (lds_void*)(bsw + (buf)*4096),       16, 0, 0); \
    __builtin_amdgcn_global_load_lds((g_void*)(bg + (kk) + 16 * DM),  (lds_void*)(bsw + (buf)*4096 + 512), 16, 0, 0); \
} while (0)

    WO_STAGE(0, 0);
    __syncthreads();
    for (int k0 = 0; k0 < DM; k0 += BK) {
        const int cur = (k0 >> 5) & 1;
        if (k0 + BK < DM) WO_STAGE(cur ^ 1, k0 + BK);
        const u16* Ac = sh + cur * 4096;
        const u16* Bc = sh + 8192 + cur * 4096;
        bf16x8 af[4], bfr[4];
#pragma unroll
        for (int mt = 0; mt < 4; mt++)
            af[mt] = *(const bf16x8*)(Ac + (wr + mt * 16 + l16) * BK + sx);
#pragma unroll
        for (int nt = 0; nt < 4; nt++)
            bfr[nt] = *(const bf16x8*)(Bc + (wc + nt * 16 + l16) * BK + sx);
#pragma unroll
        for (int mt = 0; mt < 4; mt++)
#pragma unroll
            for (int nt = 0; nt < 4; nt++)
                acc[mt][nt] = __builtin_amdgcn_mfma_f32_16x16x32_bf16(af[mt], bfr[nt], acc[mt][nt], 0, 0, 0);
        __syncthreads();
    }
#undef WO_STAGE

#pragma unroll
    for (int mt = 0; mt < 4; mt++) {
#pragma unroll
        for (int nt = 0; nt < 4; nt++) {
#pragma unroll
            for (int r = 0; r < 4; r++) {
                const int row = m0 + wr + mt * 16 + quad * 4 + r;
                const int col = n0 + wc + nt * 16 + l16;
                const size_t idx = (size_t)row * DM + col;
                out[idx] = acc[mt][nt][r] + X0[idx];
            }
        }
    }
}

// softmax + bf16-pack for one 16-row group. s0[r]: j = j0+8*quad+r; s1[r]: j += 4.
// dq = gq - j0 - 8*quad; fast <=> all dists in tile > 128.
__device__ inline bf16x8 sm_pack(f32x4 s0, f32x4 s1, int dq, bool fast,
                                 const float* rel_s, float r128) {
    float p0[4], p1[4];
    if (fast) {
#pragma unroll
        for (int r = 0; r < 4; r++) {
            p0[r] = __expf(s0[r] + (r128 - FIXMAX));
            p1[r] = __expf(s1[r] + (r128 - FIXMAX));
        }
    } else {
#pragma unroll
        for (int r = 0; r < 4; r++) {
            const int d0 = dq - r;
            const int d1 = dq - 4 - r;
            const int c0 = d0 < 0 ? 0 : (d0 > 128 ? 128 : d0);
            const int c1 = d1 < 0 ? 0 : (d1 > 128 ? 128 : d1);
            float sv0 = s0[r] + rel_s[c0];
            float sv1 = s1[r] + rel_s[c1];
            sv0 = d0 >= 0 ? sv0 : NEGBIG;
            sv1 = d1 >= 0 ? sv1 : NEGBIG;
            p0[r] = __expf(sv0 - FIXMAX);   // masked -> exp(-huge) = 0
            p1[r] = __expf(sv1 - FIXMAX);
        }
    }
    union { u32 u[4]; bf16x8 v; } pk_;      // A-frag: k = quad*8 + e
    pk_.u[0] = cvtpk(p0[0], p0[1]);
    pk_.u[1] = cvtpk(p0[2], p0[3]);
    pk_.u[2] = cvtpk(p1[0], p1[1]);
    pk_.u[3] = cvtpk(p1[2], p1[3]);
    return pk_.v;
}

// ---------------- Flash attention: K/V register reuse across 2 q-row groups ------
// Each rg-wave owns 32 q rows (groups lo/hi); one K/V load feeds 2 QK^T + 2 PV.
// Block = 128-row q-tile, paired {p, 15-p}; grid (8, B*H) = 512 blocks, XCD
// remap keeps 8 bh per XCD (KV L2-resident). jg = w>>2 splits j-range; fixed-max
// softmax stays additive so jg partials combine as o+=o', l+=l'.
__global__ __launch_bounds__(512, 4) void attn_kernel(const u16* __restrict__ Q,
        const u16* __restrict__ K, const u16* __restrict__ Vt,
        const float* __restrict__ rel, u16* __restrict__ y) {
    const int id = blockIdx.x + 8 * blockIdx.y;     // 0..511
    const int xcd = id & 7;
    const int idx = id >> 3;                        // 0..63
    const int bh = xcd * 8 + (idx & 7);             // 8 bh per XCD
    const int p = idx >> 3;                         // 0..7
    const int h = bh & (NH - 1);
    const int b = bh >> 4;
    const int tid = threadIdx.x;
    const int w = tid >> 6, lane = tid & 63;
    const int rg = w & 3, jg = w >> 2;
    const int quad = lane >> 4, l16 = lane & 15;

    __shared__ alignas(16) float rel_s[NREL];
    __shared__ alignas(16) f32x4 cb[4][2][5][64];   // 40 KB combine buffer
    __shared__ alignas(16) u16 st_s[4][1024];       // 8 KB y-store staging
    if (tid < NREL) rel_s[tid] = rel[h * NREL + tid];
    __syncthreads();
    const float r128 = rel_s[128];

    const u16* Qh = Q  + (size_t)bh * TSEQ * DH;    // frag-major regions
    const u16* Kh = K  + (size_t)bh * TSEQ * DH;
    const u16* Vh = Vt + (size_t)bh * TSEQ * DH;

    bf16x8 ones;
#pragma unroll
    for (int j = 0; j < 8; j++) ones[j] = (short)0x3F80;

    for (int ti = 0; ti < 2; ti++) {
        const int qt = ti ? (15 - p) : p;
        const int lo = qt * 128 + rg * 32;          // lower 16-row group base
        const int hi = lo + 16;                     // upper 16-row group base
        const int gqL = lo + l16, gqH = hi + l16;
        const u16* qb = Qh + (size_t)(lo >> 4) * 1024 + lane * 8;
        const bf16x8 qf0L = *(const bf16x8*)(qb);
        const bf16x8 qf1L = *(const bf16x8*)(qb + 512);
        const bf16x8 qf0H = *(const bf16x8*)(qb + 1024);
        const bf16x8 qf1H = *(const bf16x8*)(qb + 1536);

        f32x4 o0[4], o1[4];
#pragma unroll
        for (int i = 0; i < 4; i++) {
            o0[i] = (f32x4){0.f, 0.f, 0.f, 0.f};
            o1[i] = (f32x4){0.f, 0.f, 0.f, 0.f};
        }
        f32x4 l0 = (f32x4){0.f, 0.f, 0.f, 0.f};
        f32x4 l1 = (f32x4){0.f, 0.f, 0.f, 0.f};

        for (int j0 = jg * 32; j0 < lo + 32; j0 += 64) {
            const u16* kb = Kh + (size_t)(j0 >> 5) * 2048 + lane * 8;
            const bf16x8 k00 = *(const bf16x8*)(kb);
            const bf16x8 k01 = *(const bf16x8*)(kb + 512);
            const bf16x8 k10 = *(const bf16x8*)(kb + 1024);
            const bf16x8 k11 = *(const bf16x8*)(kb + 1536);
            const bool doLo = j0 < hi;              // wave-uniform: lo group live

            f32x4 sH0 = (f32x4){0.f, 0.f, 0.f, 0.f};
            f32x4 sH1 = (f32x4){0.f, 0.f, 0.f, 0.f};
            sH0 = __builtin_amdgcn_mfma_f32_16x16x32_bf16(k00, qf0H, sH0, 0, 0, 0);
            sH0 = __builtin_amdgcn_mfma_f32_16x16x32_bf16(k01, qf1H, sH0, 0, 0, 0);
            sH1 = __builtin_amdgcn_mfma_f32_16x16x32_bf16(k10, qf0H, sH1, 0, 0, 0);
            sH1 = __builtin_amdgcn_mfma_f32_16x16x32_bf16(k11, qf1H, sH1, 0, 0, 0);
            f32x4 sL0 = (f32x4){0.f, 0.f, 0.f, 0.f};
            f32x4 sL1 = (f32x4){0.f, 0.f, 0.f, 0.f};
            if (doLo) {
                sL0 = __builtin_amdgcn_mfma_f32_16x16x32_bf16(k00, qf0L, sL0, 0, 0, 0);
                sL0 = __builtin_amdgcn_mfma_f32_16x16x32_bf16(k01, qf1L, sL0, 0, 0, 0);
                sL1 = __builtin_amdgcn_mfma_f32_16x16x32_bf16(k10, qf0L, sL1, 0, 0, 0);
                sL1 = __builtin_amdgcn_mfma_f32_16x16x32_bf16(k11, qf1L, sL1, 0, 0, 0);
            }

            const bf16x8 pfH = sm_pack(sH0, sH1, gqH - j0 - 8 * quad,
                                       j0 + 159 < hi, rel_s, r128);
            bf16x8 pfL = pfH;   // dummy init; only used under doLo
            if (doLo)
                pfL = sm_pack(sL0, sL1, gqL - j0 - 8 * quad,
                              j0 + 159 < lo, rel_s, r128);

            const u16* vb = Vh + (size_t)(j0 >> 5) * 2048 + lane * 8;
            bf16x8 vf[4];
#pragma unroll
            for (int dt = 0; dt < 4; dt++)
                vf[dt] = *(const bf16x8*)(vb + dt * 512);
#pragma unroll
            for (int dt = 0; dt < 4; dt++)
                o1[dt] = __builtin_amdgcn_mfma_f32_16x16x32_bf16(pfH, vf[dt], o1[dt], 0, 0, 0);
            l1 = __builtin_amdgcn_mfma_f32_16x16x32_bf16(pfH, ones, l1, 0, 0, 0);
            if (doLo) {
#pragma unroll
                for (int dt = 0; dt < 4; dt++)
                    o0[dt] = __builtin_amdgcn_mfma_f32_16x16x32_bf16(pfL, vf[dt], o0[dt], 0, 0, 0);
                l0 = __builtin_amdgcn_mfma_f32_16x16x32_bf16(pfL, ones, l0, 0, 0, 0);
            }
        }

        if (jg == 1) {
#pragma unroll
            for (int dt = 0; dt < 4; dt++) {
                cb[rg][0][dt][lane] = o0[dt];
                cb[rg][1][dt][lane] = o1[dt];
            }
            cb[rg][0][4][lane] = l0;
            cb[rg][1][4][lane] = l1;
        }
        __syncthreads();
        if (jg == 0) {
#define FINISH(G, OG, LG, BASE) do {                                         \
            _Pragma("unroll")                                                \
            for (int dt = 0; dt < 4; dt++) {                                 \
                const f32x4 op = cb[rg][G][dt][lane];                        \
                OG[dt].x += op.x; OG[dt].y += op.y;                          \
                OG[dt].z += op.z; OG[dt].w += op.w;                          \
            }                                                                \
            const f32x4 lp = cb[rg][G][4][lane];                             \
            LG.x += lp.x; LG.y += lp.y; LG.z += lp.z; LG.w += lp.w;          \
            float inv[4];                                                    \
            _Pragma("unroll")                                                \
            for (int r = 0; r < 4; r++) inv[r] = 1.0f / LG[r];               \
            u16* st = st_s[rg];                                              \
            _Pragma("unroll")                                                \
            for (int dt = 0; dt < 4; dt++)                                   \
                _Pragma("unroll")                                            \
                for (int r = 0; r < 4; r++)                                  \
                    st[(quad * 4 + r) * 64 + dt * 16 + l16] =                \
                        f2b(OG[dt][r] * inv[r]);                             \
            _Pragma("unroll")                                                \
            for (int ps = 0; ps < 2; ps++) {                                 \
                const bf16x8 vv = *(const bf16x8*)(st + ps * 512 + lane * 8);\
                const int row = (BASE) + ps * 8 + (lane >> 3);               \
                *(bf16x8*)(y + ((size_t)(b * TSEQ + row)) * DM + h * DH      \
                           + (lane & 7) * 8) = vv;                           \
            }                                                                \
        } while (0)
            FINISH(0, o0, l0, lo);
            FINISH(1, o1, l1, hi);
#undef FINISH
        }
        __syncthreads();   // cb/st reused by next ti
    }
}

extern "C" void kernel_launch(void* const* d_in, const int* in_sizes, int n_in,
                              void* d_out, int out_size, void* d_ws, size_t ws_size,
                              hipStream_t stream) {
    const float* x   = (const float*)d_in[0];
    const float* Wq  = (const float*)d_in[1];
    const float* Wk  = (const float*)d_in[2];
    const float* Wv  = (const float*)d_in[3];
    const float* Wo  = (const float*)d_in[4];
    const float* rel = (const float*)d_in[5];
    const float* gam = (const float*)d_in[6];
    const float* bet = (const float*)d_in[7];
    u16* ws = (u16*)d_ws;
    const size_t SZ = (size_t)BATCH * TSEQ * DM;
    const size_t need_bytes = 4 * SZ * sizeof(u16);

    if (n_in != 8) {
        fill_kernel<<<4096, 256, 0, stream>>>((float*)d_out, out_size, 8000.0f);
        return;
    }
    if (ws_size < need_bytes) {
        fill_kernel<<<4096, 256, 0, stream>>>((float*)d_out, out_size, 9500.0f);
        return;
    }

    u16* xn = ws;             // [B*T, D] normalized input (bf16)
    u16* Qb = ws + SZ;        // bf16 frag-major Q (pre-scaled by 1/8 via Wq)
    u16* Kb = ws + 2 * SZ;    // bf16 frag-major K
    u16* Vb = ws + 3 * SZ;    // bf16 frag-major V
    u16* y  = xn;             // attention output reuses xn region

    // bf16 weight scratch lives in d_out (33.5 MB; only written by the final
    // GEMM): [0,2MB) Wq*0.125, [2,4MB) Wk, [4,6MB) Wv. Wo-bf16 goes into Qb
    // after attn frees it.
    u16* wscr = (u16*)d_out;
    const int W4 = (DM * DM) / 4;   // 2^18 vec4 per matrix

    lncvt_kernel<<<BATCH * TSEQ + 3 * W4 / 256, 256, 0, stream>>>(
        x, gam, bet, xn, Wq, Wk, Wv, wscr);
    gemm_qkv<<<768, 512, 0, stream>>>(xn, wscr, Qb, Kb, Vb);
    attn_kernel<<<dim3(8, BATCH * NH), 512, 0, stream>>>(Qb, Kb, Vb, rel, y);
    cvt1_kernel<<<W4 / 256, 256, 0, stream>>>(Wo, Qb, W4);   // Qb free after attn
    gemm_wo<<<dim3(BATCH * TSEQ / BM, DM / BN), 256, 0, stream>>>(y, Qb, x, (float*)d_out);
}

// Round 11
// 256.318 us; speedup vs baseline: 1.5231x; 1.5231x over previous
//
#include <hip/hip_runtime.h>
#include <math.h>

#define TSEQ 2048
#define BATCH 4
#define NH 16
#define DH 64
#define DM 1024
#define NREL 129
#define NEGBIG (-1.0e30f)
#define FIXMAX 8.0f

typedef unsigned short u16;
typedef unsigned int u32;
typedef __attribute__((ext_vector_type(8))) short bf16x8;
typedef __attribute__((ext_vector_type(4))) float f32x4;
typedef __attribute__((ext_vector_type(4))) unsigned short u16x4;

typedef __attribute__((address_space(3))) void lds_void;
typedef const __attribute__((address_space(1))) void g_void;

__device__ inline u16 f2b(float f) {
    union { float f; u32 i; } c; c.f = f;
    u32 x = c.i;
    return (u16)((x + 0x7fffu + ((x >> 16) & 1u)) >> 16);
}

// packed RNE f32->bf16 pair: D.lo = bf16(lo), D.hi = bf16(hi).
// Bit-identical to f2b for positive normal/zero inputs (both RNE).
__device__ inline u32 cvtpk(float lo, float hi) {
    u32 r;
    asm("v_cvt_pk_bf16_f32 %0, %1, %2" : "=v"(r) : "v"(lo), "v"(hi));
    return r;
}

__global__ __launch_bounds__(256) void fill_kernel(float* __restrict__ out, int n, float v) {
    for (int i = blockIdx.x * 256 + threadIdx.x; i < n; i += gridDim.x * 256)
        out[i] = v;
}

// ---------------- Fused LayerNorm + weight cvt (independent work, one dispatch) --
// blocks [0, B*T): LN row; blocks [B*T, B*T + 3*2^18/256): cvt of Wq*1/8,Wk,Wv.
__global__ __launch_bounds__(256) void lncvt_kernel(const float* __restrict__ x,
        const float* __restrict__ gamma, const float* __restrict__ beta,
        u16* __restrict__ xn, const float* __restrict__ wa,
        const float* __restrict__ wb, const float* __restrict__ wc,
        u16* __restrict__ wdst) {
    const int tid = threadIdx.x;
    if (blockIdx.x >= BATCH * TSEQ) {
        const int i = (blockIdx.x - BATCH * TSEQ) * 256 + tid;  // vec4 idx
        const int m = i >> 18;
        const int j = i & 0x3FFFF;
        const float* src = m == 0 ? wa : (m == 1 ? wb : wc);
        const float scale = m == 0 ? 0.125f : 1.0f;
        f32x4 v = *(const f32x4*)(src + (size_t)j * 4);
        u16x4 o;
        o.x = f2b(v.x * scale); o.y = f2b(v.y * scale);
        o.z = f2b(v.z * scale); o.w = f2b(v.w * scale);
        *(u16x4*)(wdst + (size_t)i * 4) = o;
        return;
    }
    const int row = blockIdx.x;
    const float* xr = x + (size_t)row * DM;
    f32x4 xv = *(const f32x4*)(xr + tid * 4);
    float s = xv.x + xv.y + xv.z + xv.w;
    float s2 = xv.x*xv.x + xv.y*xv.y + xv.z*xv.z + xv.w*xv.w;
#pragma unroll
    for (int off = 32; off > 0; off >>= 1) {
        s  += __shfl_down(s, off, 64);
        s2 += __shfl_down(s2, off, 64);
    }
    __shared__ alignas(16) float red[8];
    const int wv = tid >> 6, ln = tid & 63;
    if (ln == 0) { red[wv] = s; red[4 + wv] = s2; }
    __syncthreads();
    s  = red[0] + red[1] + red[2] + red[3];
    s2 = red[4] + red[5] + red[6] + red[7];
    const float mu = s * (1.0f / DM);
    float var = s2 * (1.0f / DM) - mu * mu;
    var = var > 0.0f ? var : 0.0f;
    const float rstd = rsqrtf(var + 1e-5f);
    f32x4 gv = *(const f32x4*)(gamma + tid * 4);
    f32x4 bv = *(const f32x4*)(beta + tid * 4);
    u16x4 ov;
    ov.x = f2b((xv.x - mu) * rstd * gv.x + bv.x);
    ov.y = f2b((xv.y - mu) * rstd * gv.y + bv.y);
    ov.z = f2b((xv.z - mu) * rstd * gv.z + bv.z);
    ov.w = f2b((xv.w - mu) * rstd * gv.w + bv.w);
    *(u16x4*)(xn + (size_t)row * DM + tid * 4) = ov;
}

__global__ __launch_bounds__(256) void cvt1_kernel(const float* __restrict__ src,
        u16* __restrict__ dst, int n4) {
    const int i = blockIdx.x * 256 + threadIdx.x;
    if (i >= n4) return;
    f32x4 v = *(const f32x4*)(src + (size_t)i * 4);
    u16x4 o;
    o.x = f2b(v.x); o.y = f2b(v.y); o.z = f2b(v.z); o.w = f2b(v.w);
    *(u16x4*)(dst + (size_t)i * 4) = o;
}

// ---------------- GEMM: 128x128 tile, BK=32, 2-phase double-buffered LDS --------
// ROUND-10 LESSON (reverted): 256x128/8-wave + __launch_bounds__(512,6) forced
// VGPR <= 512/6 = 85/wave (pool is 512/SIMD, m69) -> accumulator spill to
// scratch (WRITE_SIZE 49->519MB, 3x slowdown). A 64x64-quadrant wave needs
// ~130 unified VGPR+AGPR -> max 3 waves/SIMD -> 8-wave blocks can never fit.
// This 4-wave/256-thread shape runs 3 blocks/CU (reg-limited), grid 1536 =
// exactly 2x768: no tail. Measured 68.4us.
// LDS slot-swizzle (T2, both-sides per rule #21): 64B row stride made
// ds_read_b128 an 8-way bank conflict; pre-swizzled global source slot
// (scol ^= (lane>>3)&3) + matching read XOR -> conflicts 7.6M -> 1.3M.
#define BM 128
#define BN 128
#define BK 32

// Fragment-major layouts for attention operands (pure permutations of Q/K/V).
// Qf: per bh, per 16-q block: 2 chunks (d 0-31, 32-63) of 512 u16;
//     (t,d) -> chunk (d>>5), slot = ((d>>3)&3)*16 + (t&15), e = d&7.
// Kf: per bh, per 32-j block: 4 chunks {k00,k01,k10,k11}:
//     jr=j&31: hi=(jr>>2)&1, lk=(jr&3)|((jr>>3)<<2); chunk = hi*2 + (d>>5);
//     slot = ((d>>3)&3)*16 + lk, e = d&7.
// Vf: per bh, per 32-j block: 4 chunks dt=d>>4:
//     slot = ((t>>3)&3)*16 + (d&15), e = t&7.
__global__ __launch_bounds__(256) void gemm_qkv(const u16* __restrict__ A,
        const u16* __restrict__ W3, u16* __restrict__ Qb, u16* __restrict__ Kb,
        u16* __restrict__ Vb) {
    __shared__ alignas(16) u16 sh[16384];   // A dbuf [2][4096] + B dbuf [2][4096]
    const int id = blockIdx.x + 64 * blockIdx.y;   // 0..1535
    const int xcd = id & 7;
    const int k = id >> 3;                          // 0..191
    const int xv = xcd * 8 + (k & 7);               // m-panel: 8 per XCD
    const int yv = k >> 3;                          // 0..23 (mat, n-panel)
    const int m0 = xv * BM;
    const int mat = yv >> 3;
    const int n0 = (yv & 7) * BN;
    const u16* Wb = W3 + (size_t)mat * DM * DM;
    const int tid = threadIdx.x;
    const int w = tid >> 6;
    const int lane = tid & 63;
    const int quad = lane >> 4, l16 = lane & 15;
    const int wr = (w >> 1) * 64;
    const int wc = (w & 1) * 64;

    const int c0 = w * 2;
    const int srow = c0 * 16 + (lane >> 2);
    // pre-swizzled global source slot: LDS (row,s) gets logical slot s^sigma(row),
    // sigma(row) = (row>>1)&3 = (lane>>3)&3 on the write side
    const int scol = (((lane & 3) ^ ((lane >> 3) & 3))) * 8;
    const u16* ag = A  + (size_t)(m0 + srow) * DM + scol;
    const u16* bg = Wb + (size_t)(n0 + srow) * DM + scol;
    u16* asw = sh + c0 * 512;           // + buf*4096
    u16* bsw = sh + 8192 + c0 * 512;    // + buf*4096
    // matching read swizzle: logical slot quad lives at quad ^ ((l16>>1)&3)
    const int sx = (quad ^ ((l16 >> 1) & 3)) * 8;

    f32x4 acc[4][4];
#pragma unroll
    for (int i = 0; i < 4; i++)
#pragma unroll
        for (int j = 0; j < 4; j++) acc[i][j] = (f32x4){0.f, 0.f, 0.f, 0.f};

#define QKV_STAGE(buf, kk) do { \
    __builtin_amdgcn_global_load_lds((g_void*)(ag + (kk)),            (lds_void*)(asw + (buf)*4096),       16, 0, 0); \
    __builtin_amdgcn_global_load_lds((g_void*)(ag + (kk) + 16 * DM),  (lds_void*)(asw + (buf)*4096 + 512), 16, 0, 0); \
    __builtin_amdgcn_global_load_lds((g_void*)(bg + (kk)),            (lds_void*)(bsw + (buf)*4096),       16, 0, 0); \
    __builtin_amdgcn_global_load_lds((g_void*)(bg + (kk) + 16 * DM),  (lds_void*)(bsw + (buf)*4096 + 512), 16, 0, 0); \
} while (0)

    QKV_STAGE(0, 0);
    __syncthreads();
    for (int k0 = 0; k0 < DM; k0 += BK) {
        const int cur = (k0 >> 5) & 1;
        if (k0 + BK < DM) QKV_STAGE(cur ^ 1, k0 + BK);
        const u16* Ac = sh + cur * 4096;
        const u16* Bc = sh + 8192 + cur * 4096;
        bf16x8 af[4], bfr[4];
#pragma unroll
        for (int mt = 0; mt < 4; mt++)
            af[mt] = *(const bf16x8*)(Ac + (wr + mt * 16 + l16) * BK + sx);
#pragma unroll
        for (int nt = 0; nt < 4; nt++)
            bfr[nt] = *(const bf16x8*)(Bc + (wc + nt * 16 + l16) * BK + sx);
#pragma unroll
        for (int mt = 0; mt < 4; mt++)
#pragma unroll
            for (int nt = 0; nt < 4; nt++)
                acc[mt][nt] = __builtin_amdgcn_mfma_f32_16x16x32_bf16(af[mt], bfr[nt], acc[mt][nt], 0, 0, 0);
        __syncthreads();   // drains next-tile loads (after MFMA cover) + read fence
    }
#undef QKV_STAGE

    // ---- Epilogue: per-wave 4KB LDS staging -> coalesced 1KB chunk stores ----
    u16* outb = mat == 0 ? Qb : (mat == 1 ? Kb : Vb);
    const size_t bh = (size_t)(m0 >> 11) * NH + ((n0 + wc) >> 6);
    const int tq = (m0 & 2047) + wr;                // quadrant first row in batch
    u16* stage = sh + w * 2048;                     // per-wave 4KB (buffers dead now)

#pragma unroll
    for (int p = 0; p < 2; p++) {
#pragma unroll
        for (int mt = 0; mt < 4; mt++) {
#pragma unroll
            for (int ntl = 0; ntl < 2; ntl++) {
                const int nt = p * 2 + ntl;
#pragma unroll
                for (int r = 0; r < 4; r++) {
                    const u16 val = f2b(acc[mt][nt][r]);
                    int a;
                    if (mat == 0) {
                        a = mt * 512
                          + ((ntl * 2 + (l16 >> 3)) * 16 + quad * 4 + r) * 8 + (l16 & 7);
                    } else if (mat == 1) {
                        a = ((mt >> 1) * 2 + (quad & 1)) * 512
                          + ((ntl * 2 + (l16 >> 3)) * 16 + (quad >> 1) * 4 + (mt & 1) * 8 + r) * 8
                          + (l16 & 7);
                    } else {
                        a = ((mt >> 1) * 2 + ntl) * 512
                          + (((mt * 2 + (quad >> 1)) & 3) * 16 + l16) * 8
                          + (quad & 1) * 4 + r;
                    }
                    stage[a] = val;
                }
            }
        }
        // same-wave LDS write->read (short-typed reads alias u16 stores)
#pragma unroll
        for (int c = 0; c < 4; c++) {
            const bf16x8 vv = *(const bf16x8*)(stage + c * 512 + lane * 8);
            size_t gc;
            if (mat == 0)      gc = (bh * 128 + (tq >> 4) + c) * 2 + p;
            else if (mat == 1) gc = (bh * 64 + (tq >> 5) + (c >> 1)) * 4 + (c & 1) * 2 + p;
            else               gc = (bh * 64 + (tq >> 5) + (c >> 1)) * 4 + p * 2 + (c & 1);
            *(bf16x8*)(outb + gc * 512 + lane * 8) = vv;
        }
    }
}

// Output projection + residual: out = y @ Wo^T + x0 (fp32 out).
// Same XCD remap; same 2-phase double-buffered schedule; same LDS slot-swizzle.
__global__ __launch_bounds__(256) void gemm_wo(const u16* __restrict__ A,
        const u16* __restrict__ Wb, const float* __restrict__ X0,
        float* __restrict__ out) {
    __shared__ alignas(16) u16 sh[16384];
    const int id = blockIdx.x + 64 * blockIdx.y;   // 0..511
    const int xcd = id & 7;
    const int k = id >> 3;                          // 0..63
    const int m0 = (xcd * 8 + (k & 7)) * BM;
    const int n0 = (k >> 3) * BN;
    const int tid = threadIdx.x;
    const int w = tid >> 6;
    const int lane = tid & 63;
    const int quad = lane >> 4, l16 = lane & 15;
    const int wr = (w >> 1) * 64;
    const int wc = (w & 1) * 64;

    const int c0 = w * 2;
    const int srow = c0 * 16 + (lane >> 2);
    const int scol = (((lane & 3) ^ ((lane >> 3) & 3))) * 8;
    const u16* ag = A  + (size_t)(m0 + srow) * DM + scol;
    const u16* bg = Wb + (size_t)(n0 + srow) * DM + scol;
    u16* asw = sh + c0 * 512;
    u16* bsw = sh + 8192 + c0 * 512;
    const int sx = (quad ^ ((l16 >> 1) & 3)) * 8;

    f32x4 acc[4][4];
#pragma unroll
    for (int i = 0; i < 4; i++)
#pragma unroll
        for (int j = 0; j < 4; j++) acc[i][j] = (f32x4){0.f, 0.f, 0.f, 0.f};

#define WO_STAGE(buf, kk) do { \
    __builtin_amdgcn_global_load_lds((g_void*)(ag + (kk)),            (lds_void*)(asw + (buf)*4096),       16, 0, 0); \
    __builtin_amdgcn_global_load_lds((g_void*)(ag + (kk) + 16 * DM),  (lds_void*)(asw + (buf)*4096 + 512), 16, 0, 0); \
    __builtin_amdgcn_global_load_lds((g_void*)(bg + (kk)),            (lds_void*)(bsw + (buf)*4096),       16, 0, 0); \
    __builtin_amdgcn_global_load_lds((g_void*)(bg + (kk) + 16 * DM),  (lds_void*)(bsw + (buf)*4096 + 512), 16, 0, 0); \
} while (0)

    WO_STAGE(0, 0);
    __syncthreads();
    for (int k0 = 0; k0 < DM; k0 += BK) {
        const int cur = (k0 >> 5) & 1;
        if (k0 + BK < DM) WO_STAGE(cur ^ 1, k0 + BK);
        const u16* Ac = sh + cur * 4096;
        const u16* Bc = sh + 8192 + cur * 4096;
        bf16x8 af[4], bfr[4];
#pragma unroll
        for (int mt = 0; mt < 4; mt++)
            af[mt] = *(const bf16x8*)(Ac + (wr + mt * 16 + l16) * BK + sx);
#pragma unroll
        for (int nt = 0; nt < 4; nt++)
            bfr[nt] = *(const bf16x8*)(Bc + (wc + nt * 16 + l16) * BK + sx);
#pragma unroll
        for (int mt = 0; mt < 4; mt++)
#pragma unroll
            for (int nt = 0; nt < 4; nt++)
                acc[mt][nt] = __builtin_amdgcn_mfma_f32_16x16x32_bf16(af[mt], bfr[nt], acc[mt][nt], 0, 0, 0);
        __syncthreads();
    }
#undef WO_STAGE

#pragma unroll
    for (int mt = 0; mt < 4; mt++) {
#pragma unroll
        for (int nt = 0; nt < 4; nt++) {
#pragma unroll
            for (int r = 0; r < 4; r++) {
                const int row = m0 + wr + mt * 16 + quad * 4 + r;
                const int col = n0 + wc + nt * 16 + l16;
                const size_t idx = (size_t)row * DM + col;
                out[idx] = acc[mt][nt][r] + X0[idx];
            }
        }
    }
}

// softmax + bf16-pack for one 16-row group. s0[r]: j = j0+8*quad+r; s1[r]: j += 4.
// dq = gq - j0 - 8*quad; fast <=> all dists in tile > 128.
__device__ inline bf16x8 sm_pack(f32x4 s0, f32x4 s1, int dq, bool fast,
                                 const float* rel_s, float r128) {
    float p0[4], p1[4];
    if (fast) {
#pragma unroll
        for (int r = 0; r < 4; r++) {
            p0[r] = __expf(s0[r] + (r128 - FIXMAX));
            p1[r] = __expf(s1[r] + (r128 - FIXMAX));
        }
    } else {
#pragma unroll
        for (int r = 0; r < 4; r++) {
            const int d0 = dq - r;
            const int d1 = dq - 4 - r;
            const int c0 = d0 < 0 ? 0 : (d0 > 128 ? 128 : d0);
            const int c1 = d1 < 0 ? 0 : (d1 > 128 ? 128 : d1);
            float sv0 = s0[r] + rel_s[c0];
            float sv1 = s1[r] + rel_s[c1];
            sv0 = d0 >= 0 ? sv0 : NEGBIG;
            sv1 = d1 >= 0 ? sv1 : NEGBIG;
            p0[r] = __expf(sv0 - FIXMAX);   // masked -> exp(-huge) = 0
            p1[r] = __expf(sv1 - FIXMAX);
        }
    }
    union { u32 u[4]; bf16x8 v; } pk_;      // A-frag: k = quad*8 + e
    pk_.u[0] = cvtpk(p0[0], p0[1]);
    pk_.u[1] = cvtpk(p0[2], p0[3]);
    pk_.u[2] = cvtpk(p1[0], p1[1]);
    pk_.u[3] = cvtpk(p1[2], p1[3]);
    return pk_.v;
}

// ---------------- Flash attention: K/V register reuse across 2 q-row groups ------
// Each rg-wave owns 32 q rows (groups lo/hi); one K/V load feeds 2 QK^T + 2 PV.
// Block = 128-row q-tile, paired {p, 15-p}; grid (8, B*H) = 512 blocks, XCD
// remap keeps 8 bh per XCD (KV L2-resident). jg = w>>2 splits j-range; fixed-max
// softmax stays additive so jg partials combine as o+=o', l+=l'.
__global__ __launch_bounds__(512, 4) void attn_kernel(const u16* __restrict__ Q,
        const u16* __restrict__ K, const u16* __restrict__ Vt,
        const float* __restrict__ rel, u16* __restrict__ y) {
    const int id = blockIdx.x + 8 * blockIdx.y;     // 0..511
    const int xcd = id & 7;
    const int idx = id >> 3;                        // 0..63
    const int bh = xcd * 8 + (idx & 7);             // 8 bh per XCD
    const int p = idx >> 3;                         // 0..7
    const int h = bh & (NH - 1);
    const int b = bh >> 4;
    const int tid = threadIdx.x;
    const int w = tid >> 6, lane = tid & 63;
    const int rg = w & 3, jg = w >> 2;
    const int quad = lane >> 4, l16 = lane & 15;

    __shared__ alignas(16) float rel_s[NREL];
    __shared__ alignas(16) f32x4 cb[4][2][5][64];   // 40 KB combine buffer
    __shared__ alignas(16) u16 st_s[4][1024];       // 8 KB y-store staging
    if (tid < NREL) rel_s[tid] = rel[h * NREL + tid];
    __syncthreads();
    const float r128 = rel_s[128];

    const u16* Qh = Q  + (size_t)bh * TSEQ * DH;    // frag-major regions
    const u16* Kh = K  + (size_t)bh * TSEQ * DH;
    const u16* Vh = Vt + (size_t)bh * TSEQ * DH;

    bf16x8 ones;
#pragma unroll
    for (int j = 0; j < 8; j++) ones[j] = (short)0x3F80;

    for (int ti = 0; ti < 2; ti++) {
        const int qt = ti ? (15 - p) : p;
        const int lo = qt * 128 + rg * 32;          // lower 16-row group base
        const int hi = lo + 16;                     // upper 16-row group base
        const int gqL = lo + l16, gqH = hi + l16;
        const u16* qb = Qh + (size_t)(lo >> 4) * 1024 + lane * 8;
        const bf16x8 qf0L = *(const bf16x8*)(qb);
        const bf16x8 qf1L = *(const bf16x8*)(qb + 512);
        const bf16x8 qf0H = *(const bf16x8*)(qb + 1024);
        const bf16x8 qf1H = *(const bf16x8*)(qb + 1536);

        f32x4 o0[4], o1[4];
#pragma unroll
        for (int i = 0; i < 4; i++) {
            o0[i] = (f32x4){0.f, 0.f, 0.f, 0.f};
            o1[i] = (f32x4){0.f, 0.f, 0.f, 0.f};
        }
        f32x4 l0 = (f32x4){0.f, 0.f, 0.f, 0.f};
        f32x4 l1 = (f32x4){0.f, 0.f, 0.f, 0.f};

        for (int j0 = jg * 32; j0 < lo + 32; j0 += 64) {
            const u16* kb = Kh + (size_t)(j0 >> 5) * 2048 + lane * 8;
            const bf16x8 k00 = *(const bf16x8*)(kb);
            const bf16x8 k01 = *(const bf16x8*)(kb + 512);
            const bf16x8 k10 = *(const bf16x8*)(kb + 1024);
            const bf16x8 k11 = *(const bf16x8*)(kb + 1536);
            const bool doLo = j0 < hi;              // wave-uniform: lo group live

            f32x4 sH0 = (f32x4){0.f, 0.f, 0.f, 0.f};
            f32x4 sH1 = (f32x4){0.f, 0.f, 0.f, 0.f};
            sH0 = __builtin_amdgcn_mfma_f32_16x16x32_bf16(k00, qf0H, sH0, 0, 0, 0);
            sH0 = __builtin_amdgcn_mfma_f32_16x16x32_bf16(k01, qf1H, sH0, 0, 0, 0);
            sH1 = __builtin_amdgcn_mfma_f32_16x16x32_bf16(k10, qf0H, sH1, 0, 0, 0);
            sH1 = __builtin_amdgcn_mfma_f32_16x16x32_bf16(k11, qf1H, sH1, 0, 0, 0);
            f32x4 sL0 = (f32x4){0.f, 0.f, 0.f, 0.f};
            f32x4 sL1 = (f32x4){0.f, 0.f, 0.f, 0.f};
            if (doLo) {
                sL0 = __builtin_amdgcn_mfma_f32_16x16x32_bf16(k00, qf0L, sL0, 0, 0, 0);
                sL0 = __builtin_amdgcn_mfma_f32_16x16x32_bf16(k01, qf1L, sL0, 0, 0, 0);
                sL1 = __builtin_amdgcn_mfma_f32_16x16x32_bf16(k10, qf0L, sL1, 0, 0, 0);
                sL1 = __builtin_amdgcn_mfma_f32_16x16x32_bf16(k11, qf1L, sL1, 0, 0, 0);
            }

            const bf16x8 pfH = sm_pack(sH0, sH1, gqH - j0 - 8 * quad,
                                       j0 + 159 < hi, rel_s, r128);
            bf16x8 pfL = pfH;   // dummy init; only used under doLo
            if (doLo)
                pfL = sm_pack(sL0, sL1, gqL - j0 - 8 * quad,
                              j0 + 159 < lo, rel_s, r128);

            const u16* vb = Vh + (size_t)(j0 >> 5) * 2048 + lane * 8;
            bf16x8 vf[4];
#pragma unroll
            for (int dt = 0; dt < 4; dt++)
                vf[dt] = *(const bf16x8*)(vb + dt * 512);
#pragma unroll
            for (int dt = 0; dt < 4; dt++)
                o1[dt] = __builtin_amdgcn_mfma_f32_16x16x32_bf16(pfH, vf[dt], o1[dt], 0, 0, 0);
            l1 = __builtin_amdgcn_mfma_f32_16x16x32_bf16(pfH, ones, l1, 0, 0, 0);
            if (doLo) {
#pragma unroll
                for (int dt = 0; dt < 4; dt++)
                    o0[dt] = __builtin_amdgcn_mfma_f32_16x16x32_bf16(pfL, vf[dt], o0[dt], 0, 0, 0);
                l0 = __builtin_amdgcn_mfma_f32_16x16x32_bf16(pfL, ones, l0, 0, 0, 0);
            }
        }

        if (jg == 1) {
#pragma unroll
            for (int dt = 0; dt < 4; dt++) {
                cb[rg][0][dt][lane] = o0[dt];
                cb[rg][1][dt][lane] = o1[dt];
            }
            cb[rg][0][4][lane] = l0;
            cb[rg][1][4][lane] = l1;
        }
        __syncthreads();
        if (jg == 0) {
#define FINISH(G, OG, LG, BASE) do {                                         \
            _Pragma("unroll")                                                \
            for (int dt = 0; dt < 4; dt++) {                                 \
                const f32x4 op = cb[rg][G][dt][lane];                        \
                OG[dt].x += op.x; OG[dt].y += op.y;                          \
                OG[dt].z += op.z; OG[dt].w += op.w;                          \
            }                                                                \
            const f32x4 lp = cb[rg][G][4][lane];                             \
            LG.x += lp.x; LG.y += lp.y; LG.z += lp.z; LG.w += lp.w;          \
            float inv[4];                                                    \
            _Pragma("unroll")                                                \
            for (int r = 0; r < 4; r++) inv[r] = 1.0f / LG[r];               \
            u16* st = st_s[rg];                                              \
            _Pragma("unroll")                                                \
            for (int dt = 0; dt < 4; dt++)                                   \
                _Pragma("unroll")                                            \
                for (int r = 0; r < 4; r++)                                  \
                    st[(quad * 4 + r) * 64 + dt * 16 + l16] =                \
                        f2b(OG[dt][r] * inv[r]);                             \
            _Pragma("unroll")                                                \
            for (int ps = 0; ps < 2; ps++) {                                 \
                const bf16x8 vv = *(const bf16x8*)(st + ps * 512 + lane * 8);\
                const int row = (BASE) + ps * 8 + (lane >> 3);               \
                *(bf16x8*)(y + ((size_t)(b * TSEQ + row)) * DM + h * DH      \
                           + (lane & 7) * 8) = vv;                           \
            }                                                                \
        } while (0)
            FINISH(0, o0, l0, lo);
            FINISH(1, o1, l1, hi);
#undef FINISH
        }
        __syncthreads();   // cb/st reused by next ti
    }
}

extern "C" void kernel_launch(void* const* d_in, const int* in_sizes, int n_in,
                              void* d_out, int out_size, void* d_ws, size_t ws_size,
                              hipStream_t stream) {
    const float* x   = (const float*)d_in[0];
    const float* Wq  = (const float*)d_in[1];
    const float* Wk  = (const float*)d_in[2];
    const float* Wv  = (const float*)d_in[3];
    const float* Wo  = (const float*)d_in[4];
    const float* rel = (const float*)d_in[5];
    const float* gam = (const float*)d_in[6];
    const float* bet = (const float*)d_in[7];
    u16* ws = (u16*)d_ws;
    const size_t SZ = (size_t)BATCH * TSEQ * DM;
    const size_t need_bytes = 4 * SZ * sizeof(u16);

    if (n_in != 8) {
        fill_kernel<<<4096, 256, 0, stream>>>((float*)d_out, out_size, 8000.0f);
        return;
    }
    if (ws_size < need_bytes) {
        fill_kernel<<<4096, 256, 0, stream>>>((float*)d_out, out_size, 9500.0f);
        return;
    }

    u16* xn = ws;             // [B*T, D] normalized input (bf16)
    u16* Qb = ws + SZ;        // bf16 frag-major Q (pre-scaled by 1/8 via Wq)
    u16* Kb = ws + 2 * SZ;    // bf16 frag-major K
    u16* Vb = ws + 3 * SZ;    // bf16 frag-major V
    u16* y  = xn;             // attention output reuses xn region

    // bf16 weight scratch lives in d_out (33.5 MB; only written by the final
    // GEMM): [0,2MB) Wq*0.125, [2,4MB) Wk, [4,6MB) Wv. Wo-bf16 goes into Qb
    // after attn frees it.
    u16* wscr = (u16*)d_out;
    const int W4 = (DM * DM) / 4;   // 2^18 vec4 per matrix

    lncvt_kernel<<<BATCH * TSEQ + 3 * W4 / 256, 256, 0, stream>>>(
        x, gam, bet, xn, Wq, Wk, Wv, wscr);
    gemm_qkv<<<dim3(BATCH * TSEQ / BM, 24), 256, 0, stream>>>(xn, wscr, Qb, Kb, Vb);
    attn_kernel<<<dim3(8, BATCH * NH), 512, 0, stream>>>(Qb, Kb, Vb, rel, y);
    cvt1_kernel<<<W4 / 256, 256, 0, stream>>>(Wo, Qb, W4);   // Qb free after attn
    gemm_wo<<<dim3(BATCH * TSEQ / BM, DM / BN), 256, 0, stream>>>(y, Qb, x, (float*)d_out);
}